// Round 6
// baseline (158.371 us; speedup 1.0000x reference)
//
#include <hip/hip_runtime.h>

// B=4, D=8 -> G=32 graphs, N=2000 nodes, E=32000 edges (+N self loops),
// EMB=32, H=4 heads, C=32 -> H*C=128. ALL fp32 (reference is pure float32;
// round-1 NaN proved fp32 inputs; round-5 off-bf16-grid error proved fp32
// output comparison).
#define NODES  2000
#define GRAPHS 32
#define NEDGE  32000
#define EMBD   32
#define HEADS  4
#define CDIM   32
#define HC     128
#define NEG_SLOPE 0.2f

// Static device scratch (~1.2 MB): independent of ws_size, rewritten fully
// every launch -> graph-capture safe.
__device__ float g_t [NODES * HC];      // per-token transformed rows (1 MB)
__device__ float g_ts[NODES * HEADS];   // <t[v,h,:], att_src[h,:]>
__device__ float g_td[NODES * HEADS];   // <t[v,h,:], att_dst[h,:]>
__device__ int   g_cnt[NODES];
__device__ int   g_off[NODES + 1];
__device__ int   g_cur[NODES];
__device__ int   g_src[NEDGE];          // dst-sorted source node ids

__device__ __forceinline__ float lrelu(float z) {
    return z >= 0.f ? z : NEG_SLOPE * z;
}

// ---------------------------------------------------------------------------
// Kernel 1: per-token tables. hl[g,n] depends only on token value x[g,n], so
// compute once per token v: t[v,j] = sum_d emb[v,d]*lw[d,j], plus the two
// attention dots. 128 threads per token (2 tokens / 256-block). Also zeroes
// the CSR counters (first 8 blocks).
// ---------------------------------------------------------------------------
__global__ __launch_bounds__(256) void k_tables(
    const float* __restrict__ emb,
    const float* __restrict__ lw,
    const float* __restrict__ asrc,
    const float* __restrict__ adst)
{
    int v = blockIdx.x * 2 + (threadIdx.x >> 7);
    int j = threadIdx.x & 127;          // h = j>>5, c = j&31

    {   // zero CSR counters: blocks 0..7 cover 2048 >= 2000
        int i = blockIdx.x * 256 + threadIdx.x;
        if (i < NODES) g_cnt[i] = 0;
    }
    if (v >= NODES) return;

    float acc = 0.f;
#pragma unroll
    for (int d = 0; d < EMBD; ++d)
        acc = fmaf(emb[v * EMBD + d], lw[d * HC + j], acc);
    g_t[v * HC + j] = acc;

    int h = j >> 5, c = j & 31;
    float ps = acc * asrc[h * CDIM + c];
    float pd = acc * adst[h * CDIM + c];
#pragma unroll
    for (int m = 16; m >= 1; m >>= 1) {
        ps += __shfl_xor(ps, m);
        pd += __shfl_xor(pd, m);
    }
    if (c == 0) {
        g_ts[v * HEADS + h] = ps;
        g_td[v * HEADS + h] = pd;
    }
}

// ---------------------------------------------------------------------------
// CSR build by dst over the shared edge list. Self loops are implicit
// (k_main adds one per node), matching the reference's unconditional concat.
// ---------------------------------------------------------------------------
__global__ void k_count(const int* __restrict__ adj)
{
    int e = blockIdx.x * blockDim.x + threadIdx.x;
    if (e < NEDGE) atomicAdd(&g_cnt[adj[NEDGE + e]], 1);
}

__global__ void k_scan()   // single wave exclusive scan
{
    int lane = threadIdx.x;
    int base = 0;
    for (int start = 0; start < NODES; start += 64) {
        int i = start + lane;
        int v = (i < NODES) ? g_cnt[i] : 0;
        int incl = v;
#pragma unroll
        for (int d = 1; d < 64; d <<= 1) {
            int t = __shfl_up(incl, d);
            if (lane >= d) incl += t;
        }
        int excl = base + incl - v;
        if (i < NODES) { g_off[i] = excl; g_cur[i] = excl; }
        base += __shfl(incl, 63);
    }
    if (lane == 0) g_off[NODES] = base;   // == NEDGE
}

__global__ void k_scatter(const int* __restrict__ adj)
{
    int e = blockIdx.x * blockDim.x + threadIdx.x;
    if (e < NEDGE) {
        int s = adj[e];
        int d = adj[NEDGE + e];
        int pos = atomicAdd(&g_cur[d], 1);
        g_src[pos] = s;
    }
}

// ---------------------------------------------------------------------------
// Main kernel: 16 threads per (g,n); thread t -> head h=t>>2, c-slice j0=t*8.
// Pass 1: segment max of leaky-relu logits (incl. implicit self loop).
// Pass 2: fused exp-sum + float4 gather-FMA; normalize, +bias, fp32 store.
// ---------------------------------------------------------------------------
__global__ __launch_bounds__(256) void k_main(
    const int* __restrict__ x,
    const float* __restrict__ bias,
    float* __restrict__ out)
{
    int gid = blockIdx.x * 16 + (threadIdx.x >> 4);   // g*NODES + n, grid exact
    int t   = threadIdx.x & 15;
    int g = gid / NODES;
    int n = gid - g * NODES;
    int h  = t >> 2;
    int j0 = t * 8;                    // == h*32 + (t&3)*8

    const int* xg = x + g * NODES;
    int tokn = xg[n];
    float ad = g_td[tokn * HEADS + h];

    int beg = g_off[n];
    int end = g_off[n + 1];

    // pass 1: max logit (self loop included)
    float zself = lrelu(g_ts[tokn * HEADS + h] + ad);
    float m = zself;
    for (int p = beg; p < end; ++p) {
        int tk = xg[g_src[p]];
        float z = lrelu(g_ts[tk * HEADS + h] + ad);
        m = fmaxf(m, z);
    }

    // pass 2: exp-sum + accumulate (self loop first)
    float ssum = __expf(zself - m);
    float a0, a1, a2, a3, a4, a5, a6, a7;
    {
        const float4* row = (const float4*)(g_t + tokn * HC + j0);
        float4 r0 = row[0], r1 = row[1];
        a0 = ssum * r0.x; a1 = ssum * r0.y; a2 = ssum * r0.z; a3 = ssum * r0.w;
        a4 = ssum * r1.x; a5 = ssum * r1.y; a6 = ssum * r1.z; a7 = ssum * r1.w;
    }
    for (int p = beg; p < end; ++p) {
        int tk = xg[g_src[p]];
        float z = lrelu(g_ts[tk * HEADS + h] + ad);
        float w = __expf(z - m);
        ssum += w;
        const float4* row = (const float4*)(g_t + tk * HC + j0);
        float4 r0 = row[0], r1 = row[1];
        a0 = fmaf(w, r0.x, a0); a1 = fmaf(w, r0.y, a1);
        a2 = fmaf(w, r0.z, a2); a3 = fmaf(w, r0.w, a3);
        a4 = fmaf(w, r1.x, a4); a5 = fmaf(w, r1.y, a5);
        a6 = fmaf(w, r1.z, a6); a7 = fmaf(w, r1.w, a7);
    }

    float inv = 1.f / ssum;
    const float4* bp = (const float4*)(bias + j0);
    float4 b0 = bp[0], b1 = bp[1];
    float4 o0, o1;
    o0.x = fmaf(a0, inv, b0.x); o0.y = fmaf(a1, inv, b0.y);
    o0.z = fmaf(a2, inv, b0.z); o0.w = fmaf(a3, inv, b0.w);
    o1.x = fmaf(a4, inv, b1.x); o1.y = fmaf(a5, inv, b1.y);
    o1.z = fmaf(a6, inv, b1.z); o1.w = fmaf(a7, inv, b1.w);

    float4* op = (float4*)(out + (size_t)gid * HC + j0);
    op[0] = o0;
    op[1] = o1;
}

// ---------------------------------------------------------------------------
extern "C" void kernel_launch(void* const* d_in, const int* in_sizes, int n_in,
                              void* d_out, int out_size, void* d_ws, size_t ws_size,
                              hipStream_t stream)
{
    (void)in_sizes; (void)n_in; (void)out_size; (void)d_ws; (void)ws_size;

    const int*   x    = (const int*)d_in[0];     // [G, N]
    const int*   adj  = (const int*)d_in[1];     // [2, E]
    const float* emb  = (const float*)d_in[2];   // [N, EMB]
    const float* lw   = (const float*)d_in[3];   // [EMB, H*C]
    const float* asrc = (const float*)d_in[4];   // [H, C]
    const float* adst = (const float*)d_in[5];   // [H, C]
    const float* bias = (const float*)d_in[6];   // [H*C]
    float*       out  = (float*)d_out;           // [G, N, H*C] fp32

    k_tables<<<NODES / 2, 256, 0, stream>>>(emb, lw, asrc, adst);
    k_count <<<(NEDGE + 255) / 256, 256, 0, stream>>>(adj);
    k_scan  <<<1, 64, 0, stream>>>();
    k_scatter<<<(NEDGE + 255) / 256, 256, 0, stream>>>(adj);
    k_main  <<<(GRAPHS * NODES) / 16, 256, 0, stream>>>(x, bias, out);
}